// Round 1
// baseline (1090.956 us; speedup 1.0000x reference)
//
#include <hip/hip_runtime.h>
#include <hip/hip_bf16.h>

// ---------------------------------------------------------------------------
// EdgeClassifier: 2-layer GraphSAGE (mean agg) + edge-scoring MLP.
//   h1 = relu((segsum(x[src])/deg) @ W1l + b1l + x @ W1r)
//   h2 = relu((segsum(h1[src])/deg) @ W2l + b2l + h1 @ W2r)
//   out[e] = relu([h2[src]|h2[dst]|ea] @ Wm1 + bm1) @ Wm2 + bm2
// N=50000, E=800000, C=HID=64, EDGE_DIM=16, MLP_IN=144. All fp32.
// ---------------------------------------------------------------------------

#define C 64
#define MLP_IN 144

// ---- degree -----------------------------------------------------------------
__global__ void deg_count(const int* __restrict__ dst, float* __restrict__ deg, int E) {
    int e = blockIdx.x * blockDim.x + threadIdx.x;
    if (e < E) atomicAdd(&deg[dst[e]], 1.0f);
}

__global__ void deg_invert(float* __restrict__ deg, int N) {
    int i = blockIdx.x * blockDim.x + threadIdx.x;
    if (i < N) deg[i] = 1.0f / fmaxf(deg[i], 1.0f);
}

// ---- scatter-add of 64-ch feature rows -------------------------------------
__global__ void scatter_add(const float* __restrict__ feat, const int* __restrict__ src,
                            const int* __restrict__ dst, float* __restrict__ agg, int E) {
    int idx = blockIdx.x * blockDim.x + threadIdx.x;
    int e = idx >> 6;
    if (e >= E) return;
    int c = idx & 63;
    atomicAdd(&agg[(size_t)dst[e] * C + c], feat[(size_t)src[e] * C + c]);
}

// ---- dense SAGE layer: out = relu(agg*deg_inv @ Wl + bl + xin @ Wr) --------
// 16 nodes / block of 256. Thread tile: 1 node x 4 out-channels.
#define DN 16
__global__ __launch_bounds__(256) void dense_sage(
        const float* __restrict__ agg, const float* __restrict__ xin,
        const float* __restrict__ deg_inv,
        const float* __restrict__ Wl, const float* __restrict__ bl,
        const float* __restrict__ Wr, float* __restrict__ out, int N) {
    __shared__ float sWl[C * C];
    __shared__ float sWr[C * C];
    __shared__ float sA[DN][C + 1];
    __shared__ float sX[DN][C + 1];
    int t = threadIdx.x;
    for (int i = t; i < C * C; i += 256) { sWl[i] = Wl[i]; sWr[i] = Wr[i]; }

    int n0 = blockIdx.x * DN;
    int c = t & 63, nl = t >> 6;           // 4 nodes per pass
    for (int p = 0; p < DN / 4; ++p) {
        int nloc = p * 4 + nl;
        int n = n0 + nloc;
        float a = 0.f, xv = 0.f;
        if (n < N) {
            float di = deg_inv[n];
            a = agg[(size_t)n * C + c] * di;
            xv = xin[(size_t)n * C + c];
        }
        sA[nloc][c] = a;
        sX[nloc][c] = xv;
    }
    __syncthreads();

    int c4 = (t & 15) * 4, nr = t >> 4;    // nr in 0..15
    float a0 = 0.f, a1 = 0.f, a2 = 0.f, a3 = 0.f;
    const float* wl = &sWl[c4];
    const float* wr = &sWr[c4];
    #pragma unroll 8
    for (int k = 0; k < C; ++k) {
        float a = sA[nr][k], xv = sX[nr][k];
        float4 l = *(const float4*)&wl[k * C];
        float4 r = *(const float4*)&wr[k * C];
        a0 = fmaf(a, l.x, fmaf(xv, r.x, a0));
        a1 = fmaf(a, l.y, fmaf(xv, r.y, a1));
        a2 = fmaf(a, l.z, fmaf(xv, r.z, a2));
        a3 = fmaf(a, l.w, fmaf(xv, r.w, a3));
    }
    int n = n0 + nr;
    if (n < N) {
        float4 o;
        o.x = fmaxf(a0 + bl[c4 + 0], 0.f);
        o.y = fmaxf(a1 + bl[c4 + 1], 0.f);
        o.z = fmaxf(a2 + bl[c4 + 2], 0.f);
        o.w = fmaxf(a3 + bl[c4 + 3], 0.f);
        *(float4*)&out[(size_t)n * C + c4] = o;
    }
}

// ---- fused edge MLP: gather h2[src],h2[dst],ea -> relu(@Wm1+bm1) @ Wm2+bm2 -
// 32 edges / block of 256. Thread tile: 2 edges x 4 hidden channels.
#define EB 32
__global__ __launch_bounds__(256) void edge_mlp(
        const float* __restrict__ h, const int* __restrict__ src,
        const int* __restrict__ dst, const float* __restrict__ ea,
        const float* __restrict__ Wm1, const float* __restrict__ bm1,
        const float* __restrict__ Wm2, const float* __restrict__ bm2,
        float* __restrict__ out, int E) {
    __shared__ float sW[MLP_IN * C];        // 36864 B
    __shared__ float sE[MLP_IN][EB + 1];    // transposed edge input, 19008 B
    __shared__ int sSrc[EB], sDst[EB];
    int t = threadIdx.x;
    for (int i = t; i < MLP_IN * C; i += 256) sW[i] = Wm1[i];
    int e0 = blockIdx.x * EB;
    if (t < EB) {
        int e = e0 + t;
        sSrc[t] = (e < E) ? src[e] : 0;
        sDst[t] = (e < E) ? dst[e] : 0;
    }
    __syncthreads();

    int c = t & 63, el = t >> 6;           // 4 edges per pass (1 per wave)
    for (int p = 0; p < EB / 4; ++p) {
        int e = p * 4 + el;
        int s = sSrc[e], d = sDst[e];
        sE[c][e] = h[(size_t)s * C + c];
        sE[C + c][e] = h[(size_t)d * C + c];
        if (c < 16) {
            int ge = e0 + e;
            sE[2 * C + c][e] = (ge < E) ? ea[(size_t)ge * 16 + c] : 0.f;
        }
    }
    __syncthreads();

    int c4 = (t & 15) * 4, er = t >> 4;    // er in 0..15 -> edges er*2, er*2+1
    float acc00 = 0.f, acc01 = 0.f, acc02 = 0.f, acc03 = 0.f;
    float acc10 = 0.f, acc11 = 0.f, acc12 = 0.f, acc13 = 0.f;
    const float* w = &sW[c4];
    #pragma unroll 4
    for (int k = 0; k < MLP_IN; ++k) {
        float4 wv = *(const float4*)&w[k * C];
        float v0 = sE[k][er * 2];
        float v1 = sE[k][er * 2 + 1];
        acc00 = fmaf(v0, wv.x, acc00);
        acc01 = fmaf(v0, wv.y, acc01);
        acc02 = fmaf(v0, wv.z, acc02);
        acc03 = fmaf(v0, wv.w, acc03);
        acc10 = fmaf(v1, wv.x, acc10);
        acc11 = fmaf(v1, wv.y, acc11);
        acc12 = fmaf(v1, wv.z, acc12);
        acc13 = fmaf(v1, wv.w, acc13);
    }
    float4 bv = *(const float4*)&bm1[c4];
    float4 w2 = *(const float4*)&Wm2[c4];
    float p0 = fmaxf(acc00 + bv.x, 0.f) * w2.x + fmaxf(acc01 + bv.y, 0.f) * w2.y +
               fmaxf(acc02 + bv.z, 0.f) * w2.z + fmaxf(acc03 + bv.w, 0.f) * w2.w;
    float p1 = fmaxf(acc10 + bv.x, 0.f) * w2.x + fmaxf(acc11 + bv.y, 0.f) * w2.y +
               fmaxf(acc12 + bv.z, 0.f) * w2.z + fmaxf(acc13 + bv.w, 0.f) * w2.w;
    #pragma unroll
    for (int m = 8; m; m >>= 1) {
        p0 += __shfl_xor(p0, m, 16);
        p1 += __shfl_xor(p1, m, 16);
    }
    if ((t & 15) == 0) {
        int e = e0 + er * 2;
        float bb = bm2[0];
        if (e < E) out[e] = p0 + bb;
        if (e + 1 < E) out[e + 1] = p1 + bb;
    }
}

// ---------------------------------------------------------------------------
extern "C" void kernel_launch(void* const* d_in, const int* in_sizes, int n_in,
                              void* d_out, int out_size, void* d_ws, size_t ws_size,
                              hipStream_t stream) {
    const float* x   = (const float*)d_in[0];
    const int*   ei  = (const int*)d_in[1];
    const float* ea  = (const float*)d_in[2];
    const float* W1l = (const float*)d_in[3];
    const float* b1l = (const float*)d_in[4];
    const float* W1r = (const float*)d_in[5];
    const float* W2l = (const float*)d_in[6];
    const float* b2l = (const float*)d_in[7];
    const float* W2r = (const float*)d_in[8];
    const float* Wm1 = (const float*)d_in[9];
    const float* bm1 = (const float*)d_in[10];
    const float* Wm2 = (const float*)d_in[11];
    const float* bm2 = (const float*)d_in[12];
    float* out = (float*)d_out;

    const int N = in_sizes[0] / C;
    const int E = in_sizes[1] / 2;
    const int* src = ei;
    const int* dst = ei + E;

    float* ws   = (float*)d_ws;
    int    npad = (N + 63) & ~63;
    float* deg  = ws;                         // N floats (deg -> deg_inv in place)
    float* bufA = ws + npad;                  // N*64 floats (agg, then h2)
    float* bufH = bufA + (size_t)npad * C;    // N*64 floats (h1)

    hipMemsetAsync(deg, 0, (size_t)N * sizeof(float), stream);
    hipMemsetAsync(bufA, 0, (size_t)N * C * sizeof(float), stream);

    int tpb = 256;
    deg_count<<<(E + tpb - 1) / tpb, tpb, 0, stream>>>(dst, deg, E);
    deg_invert<<<(N + tpb - 1) / tpb, tpb, 0, stream>>>(deg, N);

    // layer 1
    scatter_add<<<((size_t)E * C + tpb - 1) / tpb, tpb, 0, stream>>>(x, src, dst, bufA, E);
    dense_sage<<<(N + DN - 1) / DN, tpb, 0, stream>>>(bufA, x, deg, W1l, b1l, W1r, bufH, N);

    // layer 2 (h2 written in place over agg buffer; block-local safe)
    hipMemsetAsync(bufA, 0, (size_t)N * C * sizeof(float), stream);
    scatter_add<<<((size_t)E * C + tpb - 1) / tpb, tpb, 0, stream>>>(bufH, src, dst, bufA, E);
    dense_sage<<<(N + DN - 1) / DN, tpb, 0, stream>>>(bufA, bufH, deg, W2l, b2l, W2r, bufA, N);

    // edge MLP
    edge_mlp<<<(E + EB - 1) / EB, tpb, 0, stream>>>(bufA, src, dst, ea, Wm1, bm1, Wm2, bm2, out, E);
}

// Round 2
// 645.362 us; speedup vs baseline: 1.6905x; 1.6905x over previous
//
#include <hip/hip_runtime.h>
#include <hip/hip_bf16.h>

// ---------------------------------------------------------------------------
// EdgeClassifier: 2-layer GraphSAGE (mean agg) + edge-scoring MLP.
//   h1 = relu((segsum(x[src])/deg) @ W1l + b1l + x @ W1r)        [fp32]
//   h2 = relu((segsum(h1[src])/deg) @ W2l + b2l + h1 @ W2r)      [stored bf16]
//   out[e] = relu([h2[src]|h2[dst]|ea] @ Wm1 + bm1) @ Wm2 + bm2  [bf16 MFMA]
// N=50000, E=800000, C=HID=64, EDGE_DIM=16, MLP_IN=144.
// ---------------------------------------------------------------------------

#define C 64
#define KP 168          // LDS row stride in bf16 (144 padded to 160 for K, 168 for banks)
#define TILE_E 64       // edges per MFMA tile

typedef short short8 __attribute__((ext_vector_type(8)));
typedef float f32x4 __attribute__((ext_vector_type(4)));

__device__ __forceinline__ unsigned short f2bf(float f) {
    unsigned int u = __float_as_uint(f);
    unsigned int r = (u + 0x7FFFu + ((u >> 16) & 1u)) >> 16;   // RNE
    return (unsigned short)r;
}

// ---- degree -----------------------------------------------------------------
__global__ void deg_count(const int* __restrict__ dst, float* __restrict__ deg, int E) {
    int e = blockIdx.x * blockDim.x + threadIdx.x;
    if (e < E) atomicAdd(&deg[dst[e]], 1.0f);
}

__global__ void deg_invert(float* __restrict__ deg, int N) {
    int i = blockIdx.x * blockDim.x + threadIdx.x;
    if (i < N) deg[i] = 1.0f / fmaxf(deg[i], 1.0f);
}

// ---- scatter-add of 64-ch feature rows -------------------------------------
__global__ void scatter_add(const float* __restrict__ feat, const int* __restrict__ src,
                            const int* __restrict__ dst, float* __restrict__ agg, int E) {
    int idx = blockIdx.x * blockDim.x + threadIdx.x;
    int e = idx >> 6;
    if (e >= E) return;
    int c = idx & 63;
    atomicAdd(&agg[(size_t)dst[e] * C + c], feat[(size_t)src[e] * C + c]);
}

// ---- dense SAGE layer: out = relu(agg*deg_inv @ Wl + bl + xin @ Wr) --------
// 16 nodes / block of 256. Thread tile: 1 node x 4 out-channels.
// BF16OUT: pack output row to bf16 (consumed only by the edge MLP gather).
#define DN 16
template <bool BF16OUT>
__global__ __launch_bounds__(256) void dense_sage(
        const float* __restrict__ agg, const float* __restrict__ xin,
        const float* __restrict__ deg_inv,
        const float* __restrict__ Wl, const float* __restrict__ bl,
        const float* __restrict__ Wr, void* __restrict__ outv, int N) {
    __shared__ float sWl[C * C];
    __shared__ float sWr[C * C];
    __shared__ float sA[DN][C + 1];
    __shared__ float sX[DN][C + 1];
    int t = threadIdx.x;
    for (int i = t; i < C * C; i += 256) { sWl[i] = Wl[i]; sWr[i] = Wr[i]; }

    int n0 = blockIdx.x * DN;
    int c = t & 63, nl = t >> 6;
    for (int p = 0; p < DN / 4; ++p) {
        int nloc = p * 4 + nl;
        int n = n0 + nloc;
        float a = 0.f, xv = 0.f;
        if (n < N) {
            float di = deg_inv[n];
            a = agg[(size_t)n * C + c] * di;
            xv = xin[(size_t)n * C + c];
        }
        sA[nloc][c] = a;
        sX[nloc][c] = xv;
    }
    __syncthreads();

    int c4 = (t & 15) * 4, nr = t >> 4;
    float a0 = 0.f, a1 = 0.f, a2 = 0.f, a3 = 0.f;
    const float* wl = &sWl[c4];
    const float* wr = &sWr[c4];
    #pragma unroll 8
    for (int k = 0; k < C; ++k) {
        float a = sA[nr][k], xv = sX[nr][k];
        float4 l = *(const float4*)&wl[k * C];
        float4 r = *(const float4*)&wr[k * C];
        a0 = fmaf(a, l.x, fmaf(xv, r.x, a0));
        a1 = fmaf(a, l.y, fmaf(xv, r.y, a1));
        a2 = fmaf(a, l.z, fmaf(xv, r.z, a2));
        a3 = fmaf(a, l.w, fmaf(xv, r.w, a3));
    }
    int n = n0 + nr;
    if (n < N) {
        float o0 = fmaxf(a0 + bl[c4 + 0], 0.f);
        float o1 = fmaxf(a1 + bl[c4 + 1], 0.f);
        float o2 = fmaxf(a2 + bl[c4 + 2], 0.f);
        float o3 = fmaxf(a3 + bl[c4 + 3], 0.f);
        if (BF16OUT) {
            ushort4 o;
            o.x = f2bf(o0); o.y = f2bf(o1); o.z = f2bf(o2); o.w = f2bf(o3);
            *(ushort4*)&((unsigned short*)outv)[(size_t)n * C + c4] = o;
        } else {
            float4 o = {o0, o1, o2, o3};
            *(float4*)&((float*)outv)[(size_t)n * C + c4] = o;
        }
    }
}

// ---- edge MLP via bf16 MFMA -------------------------------------------------
// Block = 256 (4 waves), grid-stride over 64-edge tiles.
// Per tile: stage [64 x 160] bf16 edge inputs in LDS; Wm1^T staged once/block,
// B-fragments (4 N-tiles x 5 K-chunks) held in registers.
// mfma_f32_16x16x32_bf16: A[m=lane&15][k=quad*8+j]; C/D col=lane&15, row=quad*4+reg.
__global__ __launch_bounds__(256) void edge_mlp_mfma(
        const unsigned short* __restrict__ hB, const int* __restrict__ src,
        const int* __restrict__ dst, const float* __restrict__ ea,
        const float* __restrict__ Wm1, const float* __restrict__ bm1,
        const float* __restrict__ Wm2, const float* __restrict__ bm2,
        float* __restrict__ out, int E, int nTiles) {
    __shared__ unsigned short sW[C][KP];       // Wm1^T as bf16: sW[n][k]
    __shared__ unsigned short sE[TILE_E][KP];  // edge inputs: sE[e][k]
    __shared__ int sS[TILE_E], sD[TILE_E];

    int t = threadIdx.x;
    int lane = t & 63, w = t >> 6;
    int l15 = lane & 15, quad = lane >> 4;

    // zero K-pad region [144, KP) of both tables (A_pad * W_pad must be 0)
    for (int i = t; i < C * 3; i += 256) {       // 64 rows x 3 chunks of 8 bf16
        int r = i / 3, cc = 144 + (i % 3) * 8;
        uint4 z = {0u, 0u, 0u, 0u};
        *(uint4*)&sW[r][cc] = z;
        *(uint4*)&sE[r][cc] = z;
    }
    // stage Wm1 [144][64] fp32 -> sW[n][k] bf16 (transposed)
    for (int i = t; i < 144 * C; i += 256) {
        int k = i >> 6, n = i & 63;
        sW[n][k] = f2bf(Wm1[i]);
    }
    __syncthreads();

    // B-fragments to registers: tile t4 covers out-ch [t4*16, t4*16+16)
    short8 bW[4][5];
    #pragma unroll
    for (int t4 = 0; t4 < 4; ++t4)
        #pragma unroll
        for (int kc = 0; kc < 5; ++kc)
            bW[t4][kc] = *(const short8*)&sW[t4 * 16 + l15][kc * 32 + quad * 8];
    float bmr[4], w2r[4];
    #pragma unroll
    for (int t4 = 0; t4 < 4; ++t4) {
        int j = t4 * 16 + l15;
        bmr[t4] = bm1[j];
        w2r[t4] = Wm2[j];
    }
    float bb = bm2[0];

    for (int tile = blockIdx.x; tile < nTiles; tile += gridDim.x) {
        int e0 = tile * TILE_E;
        __syncthreads();  // prior tile's sE reads complete
        if (t < TILE_E) {
            int e = e0 + t;
            sS[t] = (e < E) ? src[e] : 0;
            sD[t] = (e < E) ? dst[e] : 0;
        }
        // edge_attr -> sE[e][128..143]
        {
            int e = t >> 2, q = t & 3;
            int ge = e0 + e;
            float4 v = {0.f, 0.f, 0.f, 0.f};
            if (ge < E) v = *(const float4*)&ea[(size_t)ge * 16 + q * 4];
            ushort4 o;
            o.x = f2bf(v.x); o.y = f2bf(v.y); o.z = f2bf(v.z); o.w = f2bf(v.w);
            *(ushort4*)&sE[e][128 + q * 4] = o;
        }
        __syncthreads();  // sS/sD visible
        // h gather: sE[e][0..63] = hB[src[e]], sE[e][64..127] = hB[dst[e]]
        for (int i = t; i < TILE_E * 16; i += 256) {
            int e = i >> 4, seg = i & 15;
            int node = (seg < 8) ? sS[e] : sD[e];
            uint4 v = *(const uint4*)(hB + (size_t)node * C + (seg & 7) * 8);
            *(uint4*)&sE[e][seg * 8] = v;
        }
        __syncthreads();

        // MFMA: 16 edges per wave x 64 out-ch, K = 160 (5 chunks of 32)
        f32x4 acc[4] = {{0.f, 0.f, 0.f, 0.f}, {0.f, 0.f, 0.f, 0.f},
                        {0.f, 0.f, 0.f, 0.f}, {0.f, 0.f, 0.f, 0.f}};
        const unsigned short* arow = &sE[w * 16 + l15][quad * 8];
        #pragma unroll
        for (int kc = 0; kc < 5; ++kc) {
            short8 a = *(const short8*)(arow + kc * 32);
            #pragma unroll
            for (int t4 = 0; t4 < 4; ++t4)
                acc[t4] = __builtin_amdgcn_mfma_f32_16x16x32_bf16(a, bW[t4][kc], acc[t4], 0, 0, 0);
        }

        // epilogue: relu(hidden + bm1) . Wm2, reduce over 64 out-ch
        float s[4];
        #pragma unroll
        for (int r = 0; r < 4; ++r) {
            float v = 0.f;
            #pragma unroll
            for (int t4 = 0; t4 < 4; ++t4)
                v += fmaxf(acc[t4][r] + bmr[t4], 0.f) * w2r[t4];
            #pragma unroll
            for (int m = 1; m < 16; m <<= 1)
                v += __shfl_xor(v, m, 16);
            s[r] = v;
        }
        if (l15 == 0) {
            #pragma unroll
            for (int r = 0; r < 4; ++r) {
                int e = e0 + w * 16 + quad * 4 + r;
                if (e < E) out[e] = s[r] + bb;
            }
        }
    }
}

// ---------------------------------------------------------------------------
extern "C" void kernel_launch(void* const* d_in, const int* in_sizes, int n_in,
                              void* d_out, int out_size, void* d_ws, size_t ws_size,
                              hipStream_t stream) {
    const float* x   = (const float*)d_in[0];
    const int*   ei  = (const int*)d_in[1];
    const float* ea  = (const float*)d_in[2];
    const float* W1l = (const float*)d_in[3];
    const float* b1l = (const float*)d_in[4];
    const float* W1r = (const float*)d_in[5];
    const float* W2l = (const float*)d_in[6];
    const float* b2l = (const float*)d_in[7];
    const float* W2r = (const float*)d_in[8];
    const float* Wm1 = (const float*)d_in[9];
    const float* bm1 = (const float*)d_in[10];
    const float* Wm2 = (const float*)d_in[11];
    const float* bm2 = (const float*)d_in[12];
    float* out = (float*)d_out;

    const int N = in_sizes[0] / C;
    const int E = in_sizes[1] / 2;
    const int* src = ei;
    const int* dst = ei + E;

    float* ws   = (float*)d_ws;
    int    npad = (N + 63) & ~63;
    float* deg  = ws;                               // npad floats
    float* bufA = ws + npad;                        // npad*64 fp32 (agg1, agg2)
    float* bufH = bufA + (size_t)npad * C;          // npad*64 fp32 (h1)
    unsigned short* hB = (unsigned short*)(bufH + (size_t)npad * C);  // npad*64 bf16 (h2)

    hipMemsetAsync(deg, 0, (size_t)N * sizeof(float), stream);
    hipMemsetAsync(bufA, 0, (size_t)N * C * sizeof(float), stream);

    int tpb = 256;
    deg_count<<<(E + tpb - 1) / tpb, tpb, 0, stream>>>(dst, deg, E);
    deg_invert<<<(N + tpb - 1) / tpb, tpb, 0, stream>>>(deg, N);

    // layer 1 (fp32 out)
    scatter_add<<<((size_t)E * C + tpb - 1) / tpb, tpb, 0, stream>>>(x, src, dst, bufA, E);
    dense_sage<false><<<(N + DN - 1) / DN, tpb, 0, stream>>>(bufA, x, deg, W1l, b1l, W1r, bufH, N);

    // layer 2 (bf16 out -> hB)
    hipMemsetAsync(bufA, 0, (size_t)N * C * sizeof(float), stream);
    scatter_add<<<((size_t)E * C + tpb - 1) / tpb, tpb, 0, stream>>>(bufH, src, dst, bufA, E);
    dense_sage<true><<<(N + DN - 1) / DN, tpb, 0, stream>>>(bufA, bufH, deg, W2l, b2l, W2r, hB, N);

    // edge MLP (bf16 MFMA)
    int nTiles = (E + TILE_E - 1) / TILE_E;
    int grid = nTiles < 2560 ? nTiles : 2560;
    edge_mlp_mfma<<<grid, tpb, 0, stream>>>(hB, src, dst, ea, Wm1, bm1, Wm2, bm2, out, E, nTiles);
}

// Round 3
// 382.275 us; speedup vs baseline: 2.8539x; 1.6882x over previous
//
#include <hip/hip_runtime.h>
#include <hip/hip_bf16.h>

// ---------------------------------------------------------------------------
// EdgeClassifier: 2-layer GraphSAGE (mean agg) + edge-scoring MLP.
//   h1 = relu((segsum(x[src])/deg) @ W1l + b1l + x @ W1r)        [fp32]
//   h2 = relu((segsum(h1[src])/deg) @ W2l + b2l + h1 @ W2r)      [stored bf16]
//   out[e] = relu([h2[src]|h2[dst]|ea] @ Wm1 + bm1) @ Wm2 + bm2  [bf16 MFMA]
// N=50000, E=800000, C=HID=64, EDGE_DIM=16, MLP_IN=144.
// Aggregation via CSR gather (no float atomics): R2's scatter_add was pure
// RMW traffic (WRITE_SIZE == E*64*4 B exactly).
// ---------------------------------------------------------------------------

#define C 64
#define KP 168          // LDS row stride in bf16 (144 padded to 160 for K, 168 for banks)
#define TILE_E 64       // edges per MFMA tile

typedef short short8 __attribute__((ext_vector_type(8)));
typedef float f32x4 __attribute__((ext_vector_type(4)));

__device__ __forceinline__ unsigned short f2bf(float f) {
    unsigned int u = __float_as_uint(f);
    unsigned int r = (u + 0x7FFFu + ((u >> 16) & 1u)) >> 16;   // RNE
    return (unsigned short)r;
}

// ---- CSR build --------------------------------------------------------------
__global__ void deg_count_int(const int* __restrict__ dst, int* __restrict__ degi, int E) {
    int e = blockIdx.x * blockDim.x + threadIdx.x;
    if (e < E) atomicAdd(&degi[dst[e]], 1);
}

// per-block (1024 elems) exclusive scan + block totals
__global__ __launch_bounds__(256) void scan_partial(const int* __restrict__ degi,
        int* __restrict__ rowptr, int* __restrict__ partials, int N) {
    __shared__ int sWs[4];
    int t = threadIdx.x, b = blockIdx.x;
    int g0 = b * 1024 + t * 4;
    int v0 = (g0 + 0 < N) ? degi[g0 + 0] : 0;
    int v1 = (g0 + 1 < N) ? degi[g0 + 1] : 0;
    int v2 = (g0 + 2 < N) ? degi[g0 + 2] : 0;
    int v3 = (g0 + 3 < N) ? degi[g0 + 3] : 0;
    int tsum = v0 + v1 + v2 + v3;
    int lane = t & 63, w = t >> 6;
    int incl = tsum;
    #pragma unroll
    for (int m = 1; m < 64; m <<= 1) {
        int y = __shfl_up(incl, m, 64);
        if (lane >= m) incl += y;
    }
    if (lane == 63) sWs[w] = incl;
    __syncthreads();
    int wprefix = 0;
    for (int i = 0; i < w; ++i) wprefix += sWs[i];
    int run = wprefix + incl - tsum;
    if (g0 + 0 < N) rowptr[g0 + 0] = run; run += v0;
    if (g0 + 1 < N) rowptr[g0 + 1] = run; run += v1;
    if (g0 + 2 < N) rowptr[g0 + 2] = run; run += v2;
    if (g0 + 3 < N) rowptr[g0 + 3] = run;
    if (t == 255) partials[b] = wprefix + incl;
}

// single-wave exclusive scan of <=64 block totals
__global__ void scan_offsets(const int* __restrict__ partials, int* __restrict__ offsets, int nb) {
    int lane = threadIdx.x;
    int v = (lane < nb) ? partials[lane] : 0;
    int incl = v;
    #pragma unroll
    for (int m = 1; m < 64; m <<= 1) {
        int y = __shfl_up(incl, m, 64);
        if (lane >= m) incl += y;
    }
    if (lane < nb) offsets[lane] = incl - v;
}

// add block offsets; init cursor; compute deg_inv
__global__ void scan_add(int* __restrict__ rowptr, const int* __restrict__ offsets,
                         int* __restrict__ cursor, const int* __restrict__ degi,
                         float* __restrict__ deg_inv, int N, int E) {
    int i = blockIdx.x * blockDim.x + threadIdx.x;
    if (i < N) {
        int r = rowptr[i] + offsets[i >> 10];
        rowptr[i] = r;
        cursor[i] = r;
        deg_inv[i] = 1.0f / fmaxf((float)degi[i], 1.0f);
    }
    if (i == 0) rowptr[N] = E;
}

__global__ void fill_csr(const int* __restrict__ src, const int* __restrict__ dst,
                         int* __restrict__ cursor, int* __restrict__ eSrc, int E) {
    int e = blockIdx.x * blockDim.x + threadIdx.x;
    if (e < E) {
        int p = atomicAdd(&cursor[dst[e]], 1);
        eSrc[p] = src[e];
    }
}

// ---- CSR gather aggregation: one wave per node, lane = channel -------------
__global__ __launch_bounds__(256) void csr_aggregate(const float* __restrict__ feat,
        const int* __restrict__ rowptr, const int* __restrict__ eSrc,
        float* __restrict__ agg, int N) {
    int node = blockIdx.x * 4 + (threadIdx.x >> 6);
    if (node >= N) return;
    int lane = threadIdx.x & 63;
    int row = rowptr[node], end = rowptr[node + 1];
    float a0 = 0.f, a1 = 0.f, a2 = 0.f, a3 = 0.f;
    for (int j0 = row; j0 < end; j0 += 64) {
        int myid = (j0 + lane < end) ? eSrc[j0 + lane] : 0;
        int cnt = min(end - j0, 64);
        int j = 0;
        for (; j + 4 <= cnt; j += 4) {
            int s0 = __shfl(myid, j + 0, 64);
            int s1 = __shfl(myid, j + 1, 64);
            int s2 = __shfl(myid, j + 2, 64);
            int s3 = __shfl(myid, j + 3, 64);
            a0 += feat[(size_t)s0 * C + lane];
            a1 += feat[(size_t)s1 * C + lane];
            a2 += feat[(size_t)s2 * C + lane];
            a3 += feat[(size_t)s3 * C + lane];
        }
        for (; j < cnt; ++j) {
            int s = __shfl(myid, j, 64);
            a0 += feat[(size_t)s * C + lane];
        }
    }
    agg[(size_t)node * C + lane] = (a0 + a1) + (a2 + a3);
}

// ---- dense SAGE layer: out = relu(agg*deg_inv @ Wl + bl + xin @ Wr) --------
#define DN 16
template <bool BF16OUT>
__global__ __launch_bounds__(256) void dense_sage(
        const float* __restrict__ agg, const float* __restrict__ xin,
        const float* __restrict__ deg_inv,
        const float* __restrict__ Wl, const float* __restrict__ bl,
        const float* __restrict__ Wr, void* __restrict__ outv, int N) {
    __shared__ float sWl[C * C];
    __shared__ float sWr[C * C];
    __shared__ float sA[DN][C + 1];
    __shared__ float sX[DN][C + 1];
    int t = threadIdx.x;
    for (int i = t; i < C * C; i += 256) { sWl[i] = Wl[i]; sWr[i] = Wr[i]; }

    int n0 = blockIdx.x * DN;
    int c = t & 63, nl = t >> 6;
    for (int p = 0; p < DN / 4; ++p) {
        int nloc = p * 4 + nl;
        int n = n0 + nloc;
        float a = 0.f, xv = 0.f;
        if (n < N) {
            float di = deg_inv[n];
            a = agg[(size_t)n * C + c] * di;
            xv = xin[(size_t)n * C + c];
        }
        sA[nloc][c] = a;
        sX[nloc][c] = xv;
    }
    __syncthreads();

    int c4 = (t & 15) * 4, nr = t >> 4;
    float a0 = 0.f, a1 = 0.f, a2 = 0.f, a3 = 0.f;
    const float* wl = &sWl[c4];
    const float* wr = &sWr[c4];
    #pragma unroll 8
    for (int k = 0; k < C; ++k) {
        float a = sA[nr][k], xv = sX[nr][k];
        float4 l = *(const float4*)&wl[k * C];
        float4 r = *(const float4*)&wr[k * C];
        a0 = fmaf(a, l.x, fmaf(xv, r.x, a0));
        a1 = fmaf(a, l.y, fmaf(xv, r.y, a1));
        a2 = fmaf(a, l.z, fmaf(xv, r.z, a2));
        a3 = fmaf(a, l.w, fmaf(xv, r.w, a3));
    }
    int n = n0 + nr;
    if (n < N) {
        float o0 = fmaxf(a0 + bl[c4 + 0], 0.f);
        float o1 = fmaxf(a1 + bl[c4 + 1], 0.f);
        float o2 = fmaxf(a2 + bl[c4 + 2], 0.f);
        float o3 = fmaxf(a3 + bl[c4 + 3], 0.f);
        if (BF16OUT) {
            ushort4 o;
            o.x = f2bf(o0); o.y = f2bf(o1); o.z = f2bf(o2); o.w = f2bf(o3);
            *(ushort4*)&((unsigned short*)outv)[(size_t)n * C + c4] = o;
        } else {
            float4 o = {o0, o1, o2, o3};
            *(float4*)&((float*)outv)[(size_t)n * C + c4] = o;
        }
    }
}

// ---- edge MLP via bf16 MFMA (unchanged from R2) ----------------------------
__global__ __launch_bounds__(256) void edge_mlp_mfma(
        const unsigned short* __restrict__ hB, const int* __restrict__ src,
        const int* __restrict__ dst, const float* __restrict__ ea,
        const float* __restrict__ Wm1, const float* __restrict__ bm1,
        const float* __restrict__ Wm2, const float* __restrict__ bm2,
        float* __restrict__ out, int E, int nTiles) {
    __shared__ unsigned short sW[C][KP];
    __shared__ unsigned short sE[TILE_E][KP];
    __shared__ int sS[TILE_E], sD[TILE_E];

    int t = threadIdx.x;
    int lane = t & 63, w = t >> 6;
    int l15 = lane & 15, quad = lane >> 4;

    for (int i = t; i < C * 3; i += 256) {
        int r = i / 3, cc = 144 + (i % 3) * 8;
        uint4 z = {0u, 0u, 0u, 0u};
        *(uint4*)&sW[r][cc] = z;
        *(uint4*)&sE[r][cc] = z;
    }
    for (int i = t; i < 144 * C; i += 256) {
        int k = i >> 6, n = i & 63;
        sW[n][k] = f2bf(Wm1[i]);
    }
    __syncthreads();

    short8 bW[4][5];
    #pragma unroll
    for (int t4 = 0; t4 < 4; ++t4)
        #pragma unroll
        for (int kc = 0; kc < 5; ++kc)
            bW[t4][kc] = *(const short8*)&sW[t4 * 16 + l15][kc * 32 + quad * 8];
    float bmr[4], w2r[4];
    #pragma unroll
    for (int t4 = 0; t4 < 4; ++t4) {
        int j = t4 * 16 + l15;
        bmr[t4] = bm1[j];
        w2r[t4] = Wm2[j];
    }
    float bb = bm2[0];

    for (int tile = blockIdx.x; tile < nTiles; tile += gridDim.x) {
        int e0 = tile * TILE_E;
        __syncthreads();
        if (t < TILE_E) {
            int e = e0 + t;
            sS[t] = (e < E) ? src[e] : 0;
            sD[t] = (e < E) ? dst[e] : 0;
        }
        {
            int e = t >> 2, q = t & 3;
            int ge = e0 + e;
            float4 v = {0.f, 0.f, 0.f, 0.f};
            if (ge < E) v = *(const float4*)&ea[(size_t)ge * 16 + q * 4];
            ushort4 o;
            o.x = f2bf(v.x); o.y = f2bf(v.y); o.z = f2bf(v.z); o.w = f2bf(v.w);
            *(ushort4*)&sE[e][128 + q * 4] = o;
        }
        __syncthreads();
        for (int i = t; i < TILE_E * 16; i += 256) {
            int e = i >> 4, seg = i & 15;
            int node = (seg < 8) ? sS[e] : sD[e];
            uint4 v = *(const uint4*)(hB + (size_t)node * C + (seg & 7) * 8);
            *(uint4*)&sE[e][seg * 8] = v;
        }
        __syncthreads();

        f32x4 acc[4] = {{0.f, 0.f, 0.f, 0.f}, {0.f, 0.f, 0.f, 0.f},
                        {0.f, 0.f, 0.f, 0.f}, {0.f, 0.f, 0.f, 0.f}};
        const unsigned short* arow = &sE[w * 16 + l15][quad * 8];
        #pragma unroll
        for (int kc = 0; kc < 5; ++kc) {
            short8 a = *(const short8*)(arow + kc * 32);
            #pragma unroll
            for (int t4 = 0; t4 < 4; ++t4)
                acc[t4] = __builtin_amdgcn_mfma_f32_16x16x32_bf16(a, bW[t4][kc], acc[t4], 0, 0, 0);
        }

        float s[4];
        #pragma unroll
        for (int r = 0; r < 4; ++r) {
            float v = 0.f;
            #pragma unroll
            for (int t4 = 0; t4 < 4; ++t4)
                v += fmaxf(acc[t4][r] + bmr[t4], 0.f) * w2r[t4];
            #pragma unroll
            for (int m = 1; m < 16; m <<= 1)
                v += __shfl_xor(v, m, 16);
            s[r] = v;
        }
        if (l15 == 0) {
            #pragma unroll
            for (int r = 0; r < 4; ++r) {
                int e = e0 + w * 16 + quad * 4 + r;
                if (e < E) out[e] = s[r] + bb;
            }
        }
    }
}

// ---------------------------------------------------------------------------
extern "C" void kernel_launch(void* const* d_in, const int* in_sizes, int n_in,
                              void* d_out, int out_size, void* d_ws, size_t ws_size,
                              hipStream_t stream) {
    const float* x   = (const float*)d_in[0];
    const int*   ei  = (const int*)d_in[1];
    const float* ea  = (const float*)d_in[2];
    const float* W1l = (const float*)d_in[3];
    const float* b1l = (const float*)d_in[4];
    const float* W1r = (const float*)d_in[5];
    const float* W2l = (const float*)d_in[6];
    const float* b2l = (const float*)d_in[7];
    const float* W2r = (const float*)d_in[8];
    const float* Wm1 = (const float*)d_in[9];
    const float* bm1 = (const float*)d_in[10];
    const float* Wm2 = (const float*)d_in[11];
    const float* bm2 = (const float*)d_in[12];
    float* out = (float*)d_out;

    const int N = in_sizes[0] / C;
    const int E = in_sizes[1] / 2;
    const int* src = ei;
    const int* dst = ei + E;

    char* wsb = (char*)d_ws;
    int npad = (N + 1023) & ~1023;
    float* deg_inv = (float*)wsb;                      wsb += (size_t)npad * 4;
    float* bufA    = (float*)wsb;                      wsb += (size_t)npad * C * 4;
    float* bufH    = (float*)wsb;                      wsb += (size_t)npad * C * 4;
    unsigned short* hB = (unsigned short*)wsb;         wsb += (size_t)npad * C * 2;
    int* degi    = (int*)wsb;                          wsb += (size_t)npad * 4;
    int* rowptr  = (int*)wsb;                          wsb += (size_t)(npad + 64) * 4;
    int* cursor  = (int*)wsb;                          wsb += (size_t)npad * 4;
    int* eSrc    = (int*)wsb;                          wsb += (size_t)E * 4;
    int* partials = (int*)wsb;                         wsb += 64 * 4;
    int* offsets  = (int*)wsb;

    int tpb = 256;
    int nb = (N + 1023) / 1024;   // scan blocks (<=64)

    // CSR build
    hipMemsetAsync(degi, 0, (size_t)N * sizeof(int), stream);
    deg_count_int<<<(E + tpb - 1) / tpb, tpb, 0, stream>>>(dst, degi, E);
    scan_partial<<<nb, tpb, 0, stream>>>(degi, rowptr, partials, N);
    scan_offsets<<<1, 64, 0, stream>>>(partials, offsets, nb);
    scan_add<<<(N + tpb - 1) / tpb, tpb, 0, stream>>>(rowptr, offsets, cursor, degi, deg_inv, N, E);
    fill_csr<<<(E + tpb - 1) / tpb, tpb, 0, stream>>>(src, dst, cursor, eSrc, E);

    // layer 1 (fp32 out)
    csr_aggregate<<<(N + 3) / 4, tpb, 0, stream>>>(x, rowptr, eSrc, bufA, N);
    dense_sage<false><<<(N + DN - 1) / DN, tpb, 0, stream>>>(bufA, x, deg_inv, W1l, b1l, W1r, bufH, N);

    // layer 2 (bf16 out -> hB)
    csr_aggregate<<<(N + 3) / 4, tpb, 0, stream>>>(bufH, rowptr, eSrc, bufA, N);
    dense_sage<true><<<(N + DN - 1) / DN, tpb, 0, stream>>>(bufA, bufH, deg_inv, W2l, b2l, W2r, hB, N);

    // edge MLP (bf16 MFMA)
    int nTiles = (E + TILE_E - 1) / TILE_E;
    int grid = nTiles < 2560 ? nTiles : 2560;
    edge_mlp_mfma<<<grid, tpb, 0, stream>>>(hB, src, dst, ea, Wm1, bm1, Wm2, bm2, out, E, nTiles);
}

// Round 4
// 320.138 us; speedup vs baseline: 3.4078x; 1.1941x over previous
//
#include <hip/hip_runtime.h>
#include <hip/hip_bf16.h>

// ---------------------------------------------------------------------------
// EdgeClassifier: 2-layer GraphSAGE (mean agg) + edge-scoring MLP.
// Full bf16 data path (fp32 accumulate everywhere):
//   xB = bf16(x)
//   agg1 = mean-gather(xB) [CSR, fp32 acc] -> bf16
//   h1B = relu([agg1|xB] @ [W1l;W1r] + b1l)      [MFMA, K=128]
//   agg2 = mean-gather(h1B) -> bf16
//   h2B = relu([agg2|h1B] @ [W2l;W2r] + b2l)     [MFMA]
//   out[e] = relu([h2B[src]|h2B[dst]|ea] @ Wm1 + bm1) @ Wm2 + bm2
//            [MFMA, A-fragments gathered straight into registers: no LDS
//             staging, no in-loop barriers, no bank conflicts]
// N=50000, E=800000, C=64, EDGE_DIM=16, MLP K=144 padded to 160.
// ---------------------------------------------------------------------------

#define C 64
#define KP 168          // edge-MLP weight LDS row stride (shorts)
#define SK 136          // dense LDS K-stride (shorts): 272B = 68 dw = 4 mod 32
#define TILE_E 64

typedef short short8 __attribute__((ext_vector_type(8)));
typedef float f32x4 __attribute__((ext_vector_type(4)));

__device__ __forceinline__ unsigned short f2bf(float f) {
    unsigned int u = __float_as_uint(f);
    return (unsigned short)((u + 0x7FFFu + ((u >> 16) & 1u)) >> 16);   // RNE
}
__device__ __forceinline__ unsigned int pack2(float lo, float hi) {
    return (unsigned int)f2bf(lo) | ((unsigned int)f2bf(hi) << 16);
}
__device__ __forceinline__ float bflo(unsigned int u) { return __uint_as_float(u << 16); }
__device__ __forceinline__ float bfhi(unsigned int u) { return __uint_as_float(u & 0xFFFF0000u); }

// ---- CSR build (unchanged from R3 — proven) --------------------------------
__global__ void deg_count_int(const int* __restrict__ dst, int* __restrict__ degi, int E) {
    int e = blockIdx.x * blockDim.x + threadIdx.x;
    if (e < E) atomicAdd(&degi[dst[e]], 1);
}

__global__ __launch_bounds__(256) void scan_partial(const int* __restrict__ degi,
        int* __restrict__ rowptr, int* __restrict__ partials, int N) {
    __shared__ int sWs[4];
    int t = threadIdx.x, b = blockIdx.x;
    int g0 = b * 1024 + t * 4;
    int v0 = (g0 + 0 < N) ? degi[g0 + 0] : 0;
    int v1 = (g0 + 1 < N) ? degi[g0 + 1] : 0;
    int v2 = (g0 + 2 < N) ? degi[g0 + 2] : 0;
    int v3 = (g0 + 3 < N) ? degi[g0 + 3] : 0;
    int tsum = v0 + v1 + v2 + v3;
    int lane = t & 63, w = t >> 6;
    int incl = tsum;
    #pragma unroll
    for (int m = 1; m < 64; m <<= 1) {
        int y = __shfl_up(incl, m, 64);
        if (lane >= m) incl += y;
    }
    if (lane == 63) sWs[w] = incl;
    __syncthreads();
    int wprefix = 0;
    for (int i = 0; i < w; ++i) wprefix += sWs[i];
    int run = wprefix + incl - tsum;
    if (g0 + 0 < N) rowptr[g0 + 0] = run; run += v0;
    if (g0 + 1 < N) rowptr[g0 + 1] = run; run += v1;
    if (g0 + 2 < N) rowptr[g0 + 2] = run; run += v2;
    if (g0 + 3 < N) rowptr[g0 + 3] = run;
    if (t == 255) partials[b] = wprefix + incl;
}

__global__ void scan_offsets(const int* __restrict__ partials, int* __restrict__ offsets, int nb) {
    int lane = threadIdx.x;
    int v = (lane < nb) ? partials[lane] : 0;
    int incl = v;
    #pragma unroll
    for (int m = 1; m < 64; m <<= 1) {
        int y = __shfl_up(incl, m, 64);
        if (lane >= m) incl += y;
    }
    if (lane < nb) offsets[lane] = incl - v;
}

__global__ void scan_add(int* __restrict__ rowptr, const int* __restrict__ offsets,
                         int* __restrict__ cursor, const int* __restrict__ degi,
                         float* __restrict__ deg_inv, int N, int E) {
    int i = blockIdx.x * blockDim.x + threadIdx.x;
    if (i < N) {
        int r = rowptr[i] + offsets[i >> 10];
        rowptr[i] = r;
        cursor[i] = r;
        deg_inv[i] = 1.0f / fmaxf((float)degi[i], 1.0f);
    }
    if (i == 0) rowptr[N] = E;
}

__global__ void fill_csr(const int* __restrict__ src, const int* __restrict__ dst,
                         int* __restrict__ cursor, int* __restrict__ eSrc, int E) {
    int e = blockIdx.x * blockDim.x + threadIdx.x;
    if (e < E) {
        int p = atomicAdd(&cursor[dst[e]], 1);
        eSrc[p] = src[e];
    }
}

// ---- fp32 -> bf16 table convert --------------------------------------------
__global__ void to_bf16(const float* __restrict__ in, unsigned short* __restrict__ outb, int n8) {
    int i = blockIdx.x * blockDim.x + threadIdx.x;
    if (i >= n8) return;
    const float4* p = (const float4*)(in + (size_t)i * 8);
    float4 a = p[0], b = p[1];
    uint4 o;
    o.x = pack2(a.x, a.y); o.y = pack2(a.z, a.w);
    o.z = pack2(b.x, b.y); o.w = pack2(b.z, b.w);
    *(uint4*)(outb + (size_t)i * 8) = o;
}

// ---- CSR gather mean-aggregation, bf16 in / bf16 out (fp32 accumulate) -----
// One wave per node. Lane = (edge-slot s8 = lane>>3) x (channel-group ci = lane&7).
// 8 edges in flight per load instruction; butterfly-reduce slots at the end.
__global__ __launch_bounds__(256) void csr_agg_bf16(const unsigned short* __restrict__ fB,
        const int* __restrict__ rowptr, const int* __restrict__ eSrc,
        const float* __restrict__ deg_inv, unsigned short* __restrict__ aggB, int N) {
    int node = blockIdx.x * 4 + (threadIdx.x >> 6);
    if (node >= N) return;
    int lane = threadIdx.x & 63;
    int s8 = lane >> 3, ci = lane & 7;
    int row = rowptr[node], end = rowptr[node + 1];
    float a[8] = {0.f, 0.f, 0.f, 0.f, 0.f, 0.f, 0.f, 0.f};
    for (int j0 = row; j0 < end; j0 += 8) {
        int j = j0 + s8;
        if (j < end) {
            int s = eSrc[j];
            uint4 v = *(const uint4*)(fB + (size_t)s * C + ci * 8);
            a[0] += bflo(v.x); a[1] += bfhi(v.x);
            a[2] += bflo(v.y); a[3] += bfhi(v.y);
            a[4] += bflo(v.z); a[5] += bfhi(v.z);
            a[6] += bflo(v.w); a[7] += bfhi(v.w);
        }
    }
    #pragma unroll
    for (int m = 8; m < 64; m <<= 1)
        #pragma unroll
        for (int k = 0; k < 8; ++k)
            a[k] += __shfl_xor(a[k], m, 64);
    if (s8 == 0) {
        float di = deg_inv[node];
        uint4 o;
        o.x = pack2(a[0] * di, a[1] * di);
        o.y = pack2(a[2] * di, a[3] * di);
        o.z = pack2(a[4] * di, a[5] * di);
        o.w = pack2(a[6] * di, a[7] * di);
        *(uint4*)(aggB + (size_t)node * C + ci * 8) = o;
    }
}

// ---- dense SAGE layer via MFMA: h = relu([agg|x] @ [Wl;Wr] + bl) -----------
// Block 256 (4 waves), 64 nodes/block, single K=128 GEMM.
// sW holds [Wl;Wr]^T bf16 (B), sAB holds [agg|x] rows (A). sW is reused as
// the output repack buffer after MFMA (barrier-guarded).
__global__ __launch_bounds__(256) void dense_mfma(
        const unsigned short* __restrict__ aB, const unsigned short* __restrict__ xB,
        const float* __restrict__ Wl, const float* __restrict__ Wr,
        const float* __restrict__ bl, unsigned short* __restrict__ hOut, int N) {
    __shared__ unsigned short sW[C * SK];     // B: sW[n][k], later sOut[row][ch] (stride 72)
    __shared__ unsigned short sAB[C * SK];    // A: sAB[node][k]
    int t = threadIdx.x;
    int lane = t & 63, w = t >> 6;
    int l15 = lane & 15, quad = lane >> 4;
    int n0 = blockIdx.x * 64;

    // stage weights: sW[n][k] = (k<64 ? Wl[k][n] : Wr[k-64][n]) as bf16
    for (int i = t; i < 128 * C; i += 256) {
        int k = i >> 6, n = i & 63;
        float v = (k < C) ? Wl[k * C + n] : Wr[(k - C) * C + n];
        sW[n * SK + k] = f2bf(v);
    }
    // stage A rows: [agg | x], 64 rows x 16 chunks of 8 bf16
    for (int i = t; i < 64 * 16; i += 256) {
        int r = i >> 4, ch = i & 15;
        int node = n0 + r;
        uint4 v = {0u, 0u, 0u, 0u};
        if (node < N)
            v = (ch < 8) ? *(const uint4*)(aB + (size_t)node * C + ch * 8)
                         : *(const uint4*)(xB + (size_t)node * C + (ch - 8) * 8);
        *(uint4*)&sAB[r * SK + ch * 8] = v;
    }
    __syncthreads();

    short8 bW[4][4];
    #pragma unroll
    for (int t4 = 0; t4 < 4; ++t4)
        #pragma unroll
        for (int kc = 0; kc < 4; ++kc)
            bW[t4][kc] = *(const short8*)&sW[(t4 * 16 + l15) * SK + kc * 32 + quad * 8];
    float blr[4];
    #pragma unroll
    for (int t4 = 0; t4 < 4; ++t4) blr[t4] = bl[t4 * 16 + l15];

    f32x4 acc[4] = {{0.f, 0.f, 0.f, 0.f}, {0.f, 0.f, 0.f, 0.f},
                    {0.f, 0.f, 0.f, 0.f}, {0.f, 0.f, 0.f, 0.f}};
    #pragma unroll
    for (int kc = 0; kc < 4; ++kc) {
        short8 a = *(const short8*)&sAB[(w * 16 + l15) * SK + kc * 32 + quad * 8];
        #pragma unroll
        for (int t4 = 0; t4 < 4; ++t4)
            acc[t4] = __builtin_amdgcn_mfma_f32_16x16x32_bf16(a, bW[t4][kc], acc[t4], 0, 0, 0);
    }
    __syncthreads();   // all B-frag reads of sW done before repurposing as sOut

    // epilogue: bias + relu -> bf16 into sOut (stride 72), then vector store
    #pragma unroll
    for (int t4 = 0; t4 < 4; ++t4)
        #pragma unroll
        for (int r = 0; r < 4; ++r) {
            int rl = w * 16 + quad * 4 + r;
            sW[rl * 72 + t4 * 16 + l15] = f2bf(fmaxf(acc[t4][r] + blr[t4], 0.f));
        }
    __syncthreads();
    for (int i = t; i < 64 * 8; i += 256) {
        int r = i >> 3, c8 = i & 7;
        int node = n0 + r;
        if (node < N)
            *(uint4*)(hOut + (size_t)node * C + c8 * 8) = *(const uint4*)&sW[r * 72 + c8 * 8];
    }
}

// ---- edge MLP via bf16 MFMA, register-gathered A-fragments ------------------
// Block 256 (4 waves), grid-stride over 64-edge tiles; wave handles 16 edges.
// Lane (l15,quad): A[m=l15][k=quad*8+j] gathered as one uint4 per kc straight
// from global: kc0/1 = h[src] ch 0..63, kc2/3 = h[dst], kc4 = ea (quad<2) | 0.
// No LDS staging of A, no in-loop barriers.
__global__ __launch_bounds__(256) void edge_mlp_reg(
        const unsigned short* __restrict__ hB, const int* __restrict__ src,
        const int* __restrict__ dst, const float* __restrict__ ea,
        const float* __restrict__ Wm1, const float* __restrict__ bm1,
        const float* __restrict__ Wm2, const float* __restrict__ bm2,
        float* __restrict__ out, int E, int nTiles) {
    __shared__ unsigned short sW[C * KP];     // Wm1^T bf16, K zero-padded to 160
    int t = threadIdx.x;
    int lane = t & 63, w = t >> 6;
    int l15 = lane & 15, quad = lane >> 4;

    for (int i = t; i < C * 3; i += 256) {          // zero pad cols 144..167
        int r = i / 3, cc = 144 + (i % 3) * 8;
        uint4 z = {0u, 0u, 0u, 0u};
        *(uint4*)&sW[r * KP + cc] = z;
    }
    for (int i = t; i < 144 * C; i += 256) {
        int k = i >> 6, n = i & 63;
        sW[n * KP + k] = f2bf(Wm1[i]);
    }
    __syncthreads();

    short8 bW[4][5];
    #pragma unroll
    for (int t4 = 0; t4 < 4; ++t4)
        #pragma unroll
        for (int kc = 0; kc < 5; ++kc)
            bW[t4][kc] = *(const short8*)&sW[(t4 * 16 + l15) * KP + kc * 32 + quad * 8];
    float bmr[4], w2r[4];
    #pragma unroll
    for (int t4 = 0; t4 < 4; ++t4) {
        int j = t4 * 16 + l15;
        bmr[t4] = bm1[j];
        w2r[t4] = Wm2[j];
    }
    float bb = bm2[0];

    for (int tile = blockIdx.x; tile < nTiles; tile += gridDim.x) {
        int e0 = tile * TILE_E;
        int idx = e0 + w * 16 + l15;
        int idxc = (idx < E) ? idx : 0;
        int s = src[idxc], d = dst[idxc];

        const uint4* ps = (const uint4*)(hB + (size_t)s * C);
        const uint4* pd = (const uint4*)(hB + (size_t)d * C);
        uint4 u0 = ps[quad];           // src ch quad*8 .. +8   (k 0..31)
        uint4 u1 = ps[4 + quad];       // src ch 32+quad*8      (k 32..63)
        uint4 u2 = pd[quad];           // dst                   (k 64..95)
        uint4 u3 = pd[4 + quad];       //                       (k 96..127)
        uint4 u4 = {0u, 0u, 0u, 0u};   // ea | zero-pad         (k 128..159)
        if (quad < 2) {
            const float4* pe = (const float4*)(ea + (size_t)idxc * 16 + quad * 8);
            float4 f0 = pe[0], f1 = pe[1];
            u4.x = pack2(f0.x, f0.y); u4.y = pack2(f0.z, f0.w);
            u4.z = pack2(f1.x, f1.y); u4.w = pack2(f1.z, f1.w);
        }
        short8 a0 = *(short8*)&u0, a1 = *(short8*)&u1, a2 = *(short8*)&u2,
               a3 = *(short8*)&u3, a4 = *(short8*)&u4;

        f32x4 acc[4] = {{0.f, 0.f, 0.f, 0.f}, {0.f, 0.f, 0.f, 0.f},
                        {0.f, 0.f, 0.f, 0.f}, {0.f, 0.f, 0.f, 0.f}};
        #pragma unroll
        for (int t4 = 0; t4 < 4; ++t4) {
            acc[t4] = __builtin_amdgcn_mfma_f32_16x16x32_bf16(a0, bW[t4][0], acc[t4], 0, 0, 0);
            acc[t4] = __builtin_amdgcn_mfma_f32_16x16x32_bf16(a1, bW[t4][1], acc[t4], 0, 0, 0);
            acc[t4] = __builtin_amdgcn_mfma_f32_16x16x32_bf16(a2, bW[t4][2], acc[t4], 0, 0, 0);
            acc[t4] = __builtin_amdgcn_mfma_f32_16x16x32_bf16(a3, bW[t4][3], acc[t4], 0, 0, 0);
            acc[t4] = __builtin_amdgcn_mfma_f32_16x16x32_bf16(a4, bW[t4][4], acc[t4], 0, 0, 0);
        }

        float sres[4];
        #pragma unroll
        for (int r = 0; r < 4; ++r) {
            float v = 0.f;
            #pragma unroll
            for (int t4 = 0; t4 < 4; ++t4)
                v += fmaxf(acc[t4][r] + bmr[t4], 0.f) * w2r[t4];
            #pragma unroll
            for (int m = 1; m < 16; m <<= 1)
                v += __shfl_xor(v, m, 16);
            sres[r] = v;
        }
        if (l15 == 0) {
            #pragma unroll
            for (int r = 0; r < 4; ++r) {
                int e = e0 + w * 16 + quad * 4 + r;
                if (e < E) out[e] = sres[r] + bb;
            }
        }
    }
}

// ---------------------------------------------------------------------------
extern "C" void kernel_launch(void* const* d_in, const int* in_sizes, int n_in,
                              void* d_out, int out_size, void* d_ws, size_t ws_size,
                              hipStream_t stream) {
    const float* x   = (const float*)d_in[0];
    const int*   ei  = (const int*)d_in[1];
    const float* ea  = (const float*)d_in[2];
    const float* W1l = (const float*)d_in[3];
    const float* b1l = (const float*)d_in[4];
    const float* W1r = (const float*)d_in[5];
    const float* W2l = (const float*)d_in[6];
    const float* b2l = (const float*)d_in[7];
    const float* W2r = (const float*)d_in[8];
    const float* Wm1 = (const float*)d_in[9];
    const float* bm1 = (const float*)d_in[10];
    const float* Wm2 = (const float*)d_in[11];
    const float* bm2 = (const float*)d_in[12];
    float* out = (float*)d_out;

    const int N = in_sizes[0] / C;
    const int E = in_sizes[1] / 2;
    const int* src = ei;
    const int* dst = ei + E;

    char* wsb = (char*)d_ws;
    int npad = (N + 1023) & ~1023;
    float* deg_inv = (float*)wsb;               wsb += (size_t)npad * 4;
    unsigned short* xB   = (unsigned short*)wsb; wsb += (size_t)npad * C * 2;
    unsigned short* h1B  = (unsigned short*)wsb; wsb += (size_t)npad * C * 2;
    unsigned short* h2B  = (unsigned short*)wsb; wsb += (size_t)npad * C * 2;
    unsigned short* aggB = (unsigned short*)wsb; wsb += (size_t)npad * C * 2;
    int* degi    = (int*)wsb;                   wsb += (size_t)npad * 4;
    int* rowptr  = (int*)wsb;                   wsb += (size_t)(npad + 64) * 4;
    int* cursor  = (int*)wsb;                   wsb += (size_t)npad * 4;
    int* eSrc    = (int*)wsb;                   wsb += (size_t)E * 4;
    int* partials = (int*)wsb;                  wsb += 64 * 4;
    int* offsets  = (int*)wsb;

    int tpb = 256;
    int nb = (N + 1023) / 1024;

    // CSR build
    hipMemsetAsync(degi, 0, (size_t)N * sizeof(int), stream);
    deg_count_int<<<(E + tpb - 1) / tpb, tpb, 0, stream>>>(dst, degi, E);
    to_bf16<<<((N * C / 8) + tpb - 1) / tpb, tpb, 0, stream>>>(x, xB, N * C / 8);
    scan_partial<<<nb, tpb, 0, stream>>>(degi, rowptr, partials, N);
    scan_offsets<<<1, 64, 0, stream>>>(partials, offsets, nb);
    scan_add<<<(N + tpb - 1) / tpb, tpb, 0, stream>>>(rowptr, offsets, cursor, degi, deg_inv, N, E);
    fill_csr<<<(E + tpb - 1) / tpb, tpb, 0, stream>>>(src, dst, cursor, eSrc, E);

    // layer 1
    csr_agg_bf16<<<(N + 3) / 4, tpb, 0, stream>>>(xB, rowptr, eSrc, deg_inv, aggB, N);
    dense_mfma<<<(N + 63) / 64, tpb, 0, stream>>>(aggB, xB, W1l, W1r, b1l, h1B, N);

    // layer 2
    csr_agg_bf16<<<(N + 3) / 4, tpb, 0, stream>>>(h1B, rowptr, eSrc, deg_inv, aggB, N);
    dense_mfma<<<(N + 63) / 64, tpb, 0, stream>>>(aggB, h1B, W2l, W2r, b2l, h2B, N);

    // edge MLP
    int nTiles = (E + TILE_E - 1) / TILE_E;
    int grid = nTiles < 2048 ? nTiles : 2048;
    edge_mlp_reg<<<grid, tpb, 0, stream>>>(h2B, src, dst, ea, Wm1, bm1, Wm2, bm2, out, E, nTiles);
}

// Round 5
// 314.950 us; speedup vs baseline: 3.4639x; 1.0165x over previous
//
#include <hip/hip_runtime.h>
#include <hip/hip_bf16.h>

// ---------------------------------------------------------------------------
// EdgeClassifier: 2-layer GraphSAGE (mean agg) + edge-scoring MLP.
// Full bf16 data path (fp32 accumulate everywhere):
//   xB = bf16(x); eaB = bf16(edge_attr)   [fused into deg_count]
//   agg1 = mean-gather(xB) [CSR] -> bf16
//   h1B = relu([agg1|xB] @ [W1l;W1r] + b1l)      [MFMA, K=128]
//   agg2 = mean-gather(h1B) -> bf16
//   h2B = relu([agg2|h1B] @ [W2l;W2r] + b2l)     [MFMA]
//   out[e] = relu([h2B[src]|h2B[dst]|ea] @ Wm1 + bm1) @ Wm2 + bm2
//            [MFMA; A-fragments gathered straight into registers, 2-stage
//             software pipeline: next tile's gathers overlap current MFMA]
// N=50000, E=800000, C=64, EDGE_DIM=16, MLP K=144 padded to 160.
// ---------------------------------------------------------------------------

#define C 64
#define KP 168          // edge-MLP weight LDS row stride (shorts)
#define SK 136          // dense LDS K-stride (shorts)
#define TILE_E 64

typedef short short8 __attribute__((ext_vector_type(8)));
typedef float f32x4 __attribute__((ext_vector_type(4)));

__device__ __forceinline__ unsigned short f2bf(float f) {
    unsigned int u = __float_as_uint(f);
    return (unsigned short)((u + 0x7FFFu + ((u >> 16) & 1u)) >> 16);   // RNE
}
__device__ __forceinline__ unsigned int pack2(float lo, float hi) {
    return (unsigned int)f2bf(lo) | ((unsigned int)f2bf(hi) << 16);
}
__device__ __forceinline__ float bflo(unsigned int u) { return __uint_as_float(u << 16); }
__device__ __forceinline__ float bfhi(unsigned int u) { return __uint_as_float(u & 0xFFFF0000u); }

// ---- degree count + fused ea->bf16 conversion ------------------------------
// i < E: atomic degree bump. i < 2E: convert 8 floats of ea (coalesced).
__global__ void deg_count_ea(const int* __restrict__ dst, int* __restrict__ degi,
                             const float* __restrict__ ea, unsigned short* __restrict__ eaB,
                             int E, int doEa) {
    int i = blockIdx.x * blockDim.x + threadIdx.x;
    if (i < E) atomicAdd(&degi[dst[i]], 1);
    if (doEa && i < 2 * E) {
        const float4* p = (const float4*)(ea + (size_t)i * 8);
        float4 a = p[0], b = p[1];
        uint4 o;
        o.x = pack2(a.x, a.y); o.y = pack2(a.z, a.w);
        o.z = pack2(b.x, b.y); o.w = pack2(b.z, b.w);
        *(uint4*)(eaB + (size_t)i * 8) = o;
    }
}

// ---- CSR build (proven R3) --------------------------------------------------
__global__ __launch_bounds__(256) void scan_partial(const int* __restrict__ degi,
        int* __restrict__ rowptr, int* __restrict__ partials, int N) {
    __shared__ int sWs[4];
    int t = threadIdx.x, b = blockIdx.x;
    int g0 = b * 1024 + t * 4;
    int v0 = (g0 + 0 < N) ? degi[g0 + 0] : 0;
    int v1 = (g0 + 1 < N) ? degi[g0 + 1] : 0;
    int v2 = (g0 + 2 < N) ? degi[g0 + 2] : 0;
    int v3 = (g0 + 3 < N) ? degi[g0 + 3] : 0;
    int tsum = v0 + v1 + v2 + v3;
    int lane = t & 63, w = t >> 6;
    int incl = tsum;
    #pragma unroll
    for (int m = 1; m < 64; m <<= 1) {
        int y = __shfl_up(incl, m, 64);
        if (lane >= m) incl += y;
    }
    if (lane == 63) sWs[w] = incl;
    __syncthreads();
    int wprefix = 0;
    for (int i = 0; i < w; ++i) wprefix += sWs[i];
    int run = wprefix + incl - tsum;
    if (g0 + 0 < N) rowptr[g0 + 0] = run; run += v0;
    if (g0 + 1 < N) rowptr[g0 + 1] = run; run += v1;
    if (g0 + 2 < N) rowptr[g0 + 2] = run; run += v2;
    if (g0 + 3 < N) rowptr[g0 + 3] = run;
    if (t == 255) partials[b] = wprefix + incl;
}

__global__ void scan_offsets(const int* __restrict__ partials, int* __restrict__ offsets, int nb) {
    int lane = threadIdx.x;
    int v = (lane < nb) ? partials[lane] : 0;
    int incl = v;
    #pragma unroll
    for (int m = 1; m < 64; m <<= 1) {
        int y = __shfl_up(incl, m, 64);
        if (lane >= m) incl += y;
    }
    if (lane < nb) offsets[lane] = incl - v;
}

__global__ void scan_add(int* __restrict__ rowptr, const int* __restrict__ offsets,
                         int* __restrict__ cursor, const int* __restrict__ degi,
                         float* __restrict__ deg_inv, int N, int E) {
    int i = blockIdx.x * blockDim.x + threadIdx.x;
    if (i < N) {
        int r = rowptr[i] + offsets[i >> 10];
        rowptr[i] = r;
        cursor[i] = r;
        deg_inv[i] = 1.0f / fmaxf((float)degi[i], 1.0f);
    }
    if (i == 0) rowptr[N] = E;
}

__global__ void fill_csr(const int* __restrict__ src, const int* __restrict__ dst,
                         int* __restrict__ cursor, int* __restrict__ eSrc, int E) {
    int e = blockIdx.x * blockDim.x + threadIdx.x;
    if (e < E) {
        int p = atomicAdd(&cursor[dst[e]], 1);
        eSrc[p] = src[e];
    }
}

// ---- fp32 -> bf16 table convert --------------------------------------------
__global__ void to_bf16(const float* __restrict__ in, unsigned short* __restrict__ outb, int n8) {
    int i = blockIdx.x * blockDim.x + threadIdx.x;
    if (i >= n8) return;
    const float4* p = (const float4*)(in + (size_t)i * 8);
    float4 a = p[0], b = p[1];
    uint4 o;
    o.x = pack2(a.x, a.y); o.y = pack2(a.z, a.w);
    o.z = pack2(b.x, b.y); o.w = pack2(b.z, b.w);
    *(uint4*)(outb + (size_t)i * 8) = o;
}

// ---- CSR gather mean-aggregation, bf16 in/out (fp32 acc), unroll x2 --------
__global__ __launch_bounds__(256) void csr_agg_bf16(const unsigned short* __restrict__ fB,
        const int* __restrict__ rowptr, const int* __restrict__ eSrc,
        const float* __restrict__ deg_inv, unsigned short* __restrict__ aggB, int N) {
    int node = blockIdx.x * 4 + (threadIdx.x >> 6);
    if (node >= N) return;
    int lane = threadIdx.x & 63;
    int s8 = lane >> 3, ci = lane & 7;
    int row = rowptr[node], end = rowptr[node + 1];
    float a[8] = {0.f, 0.f, 0.f, 0.f, 0.f, 0.f, 0.f, 0.f};
    int j = row;
    for (; j + 16 <= end; j += 16) {            // 2 edge-groups in flight
        int sA = eSrc[j + s8];
        int sB = eSrc[j + 8 + s8];
        uint4 vA = *(const uint4*)(fB + (size_t)sA * C + ci * 8);
        uint4 vB = *(const uint4*)(fB + (size_t)sB * C + ci * 8);
        a[0] += bflo(vA.x); a[1] += bfhi(vA.x);
        a[2] += bflo(vA.y); a[3] += bfhi(vA.y);
        a[4] += bflo(vA.z); a[5] += bfhi(vA.z);
        a[6] += bflo(vA.w); a[7] += bfhi(vA.w);
        a[0] += bflo(vB.x); a[1] += bfhi(vB.x);
        a[2] += bflo(vB.y); a[3] += bfhi(vB.y);
        a[4] += bflo(vB.z); a[5] += bfhi(vB.z);
        a[6] += bflo(vB.w); a[7] += bfhi(vB.w);
    }
    for (; j < end; j += 8) {
        if (j + s8 < end) {
            int s = eSrc[j + s8];
            uint4 v = *(const uint4*)(fB + (size_t)s * C + ci * 8);
            a[0] += bflo(v.x); a[1] += bfhi(v.x);
            a[2] += bflo(v.y); a[3] += bfhi(v.y);
            a[4] += bflo(v.z); a[5] += bfhi(v.z);
            a[6] += bflo(v.w); a[7] += bfhi(v.w);
        }
    }
    #pragma unroll
    for (int m = 8; m < 64; m <<= 1)
        #pragma unroll
        for (int k = 0; k < 8; ++k)
            a[k] += __shfl_xor(a[k], m, 64);
    if (s8 == 0) {
        float di = deg_inv[node];
        uint4 o;
        o.x = pack2(a[0] * di, a[1] * di);
        o.y = pack2(a[2] * di, a[3] * di);
        o.z = pack2(a[4] * di, a[5] * di);
        o.w = pack2(a[6] * di, a[7] * di);
        *(uint4*)(aggB + (size_t)node * C + ci * 8) = o;
    }
}

// ---- dense SAGE layer via MFMA (unchanged from R4) -------------------------
__global__ __launch_bounds__(256) void dense_mfma(
        const unsigned short* __restrict__ aB, const unsigned short* __restrict__ xB,
        const float* __restrict__ Wl, const float* __restrict__ Wr,
        const float* __restrict__ bl, unsigned short* __restrict__ hOut, int N) {
    __shared__ unsigned short sW[C * SK];
    __shared__ unsigned short sAB[C * SK];
    int t = threadIdx.x;
    int lane = t & 63, w = t >> 6;
    int l15 = lane & 15, quad = lane >> 4;
    int n0 = blockIdx.x * 64;

    for (int i = t; i < 128 * C; i += 256) {
        int k = i >> 6, n = i & 63;
        float v = (k < C) ? Wl[k * C + n] : Wr[(k - C) * C + n];
        sW[n * SK + k] = f2bf(v);
    }
    for (int i = t; i < 64 * 16; i += 256) {
        int r = i >> 4, ch = i & 15;
        int node = n0 + r;
        uint4 v = {0u, 0u, 0u, 0u};
        if (node < N)
            v = (ch < 8) ? *(const uint4*)(aB + (size_t)node * C + ch * 8)
                         : *(const uint4*)(xB + (size_t)node * C + (ch - 8) * 8);
        *(uint4*)&sAB[r * SK + ch * 8] = v;
    }
    __syncthreads();

    short8 bW[4][4];
    #pragma unroll
    for (int t4 = 0; t4 < 4; ++t4)
        #pragma unroll
        for (int kc = 0; kc < 4; ++kc)
            bW[t4][kc] = *(const short8*)&sW[(t4 * 16 + l15) * SK + kc * 32 + quad * 8];
    float blr[4];
    #pragma unroll
    for (int t4 = 0; t4 < 4; ++t4) blr[t4] = bl[t4 * 16 + l15];

    f32x4 acc[4] = {{0.f, 0.f, 0.f, 0.f}, {0.f, 0.f, 0.f, 0.f},
                    {0.f, 0.f, 0.f, 0.f}, {0.f, 0.f, 0.f, 0.f}};
    #pragma unroll
    for (int kc = 0; kc < 4; ++kc) {
        short8 a = *(const short8*)&sAB[(w * 16 + l15) * SK + kc * 32 + quad * 8];
        #pragma unroll
        for (int t4 = 0; t4 < 4; ++t4)
            acc[t4] = __builtin_amdgcn_mfma_f32_16x16x32_bf16(a, bW[t4][kc], acc[t4], 0, 0, 0);
    }
    __syncthreads();

    #pragma unroll
    for (int t4 = 0; t4 < 4; ++t4)
        #pragma unroll
        for (int r = 0; r < 4; ++r) {
            int rl = w * 16 + quad * 4 + r;
            sW[rl * 72 + t4 * 16 + l15] = f2bf(fmaxf(acc[t4][r] + blr[t4], 0.f));
        }
    __syncthreads();
    for (int i = t; i < 64 * 8; i += 256) {
        int r = i >> 3, c8 = i & 7;
        int node = n0 + r;
        if (node < N)
            *(uint4*)(hOut + (size_t)node * C + c8 * 8) = *(const uint4*)&sW[r * 72 + c8 * 8];
    }
}

// ---- edge MLP: bf16 MFMA, register A-gather, 2-stage software pipeline -----
template <bool EAB>
__device__ __forceinline__ void gather_rows(const unsigned short* __restrict__ hB,
        const unsigned short* __restrict__ eaB, const float* __restrict__ ea,
        int s, int d, int idxc, int quad,
        uint4& u0, uint4& u1, uint4& u2, uint4& u3, uint4& u4) {
    const uint4* ps = (const uint4*)(hB + (size_t)s * C);
    const uint4* pd = (const uint4*)(hB + (size_t)d * C);
    u0 = ps[quad];
    u1 = ps[4 + quad];
    u2 = pd[quad];
    u3 = pd[4 + quad];
    u4.x = 0u; u4.y = 0u; u4.z = 0u; u4.w = 0u;
    if (quad < 2) {
        if (EAB) {
            u4 = *(const uint4*)(eaB + (size_t)idxc * 16 + quad * 8);
        } else {
            const float4* pe = (const float4*)(ea + (size_t)idxc * 16 + quad * 8);
            float4 f0 = pe[0], f1 = pe[1];
            u4.x = pack2(f0.x, f0.y); u4.y = pack2(f0.z, f0.w);
            u4.z = pack2(f1.x, f1.y); u4.w = pack2(f1.z, f1.w);
        }
    }
}

template <bool EAB>
__global__ __launch_bounds__(256) void edge_mlp_pipe(
        const unsigned short* __restrict__ hB, const int* __restrict__ src,
        const int* __restrict__ dst, const float* __restrict__ ea,
        const unsigned short* __restrict__ eaB,
        const float* __restrict__ Wm1, const float* __restrict__ bm1,
        const float* __restrict__ Wm2, const float* __restrict__ bm2,
        float* __restrict__ out, int E, int nTiles) {
    __shared__ unsigned short sW[C * KP];     // Wm1^T bf16, K zero-padded to 160
    int t = threadIdx.x;
    int lane = t & 63, w = t >> 6;
    int l15 = lane & 15, quad = lane >> 4;

    for (int i = t; i < C * 3; i += 256) {
        int r = i / 3, cc = 144 + (i % 3) * 8;
        uint4 z = {0u, 0u, 0u, 0u};
        *(uint4*)&sW[r * KP + cc] = z;
    }
    for (int i = t; i < 144 * C; i += 256) {
        int k = i >> 6, n = i & 63;
        sW[n * KP + k] = f2bf(Wm1[i]);
    }
    __syncthreads();

    short8 bW[4][5];
    #pragma unroll
    for (int t4 = 0; t4 < 4; ++t4)
        #pragma unroll
        for (int kc = 0; kc < 5; ++kc)
            bW[t4][kc] = *(const short8*)&sW[(t4 * 16 + l15) * KP + kc * 32 + quad * 8];
    float bmr[4], w2r[4];
    #pragma unroll
    for (int t4 = 0; t4 < 4; ++t4) {
        int j = t4 * 16 + l15;
        bmr[t4] = bm1[j];
        w2r[t4] = Wm2[j];
    }
    float bb = bm2[0];

    int stride = gridDim.x;
    int lbase = w * 16 + l15;

    // pipeline prologue: indices for tile and tile+stride, rows for tile
    int tile = blockIdx.x;
    int idxc = min(tile * TILE_E + lbase, E - 1);
    int s = src[idxc], d = dst[idxc];
    int tileN = tile + stride;
    int idxNc = (tileN < nTiles) ? min(tileN * TILE_E + lbase, E - 1) : idxc;
    int sN = src[idxNc], dN = dst[idxNc];
    uint4 cu0, cu1, cu2, cu3, cu4;
    gather_rows<EAB>(hB, eaB, ea, s, d, idxc, quad, cu0, cu1, cu2, cu3, cu4);

    while (true) {
        bool hasNext = (tileN < nTiles);
        // prefetch next tile's rows (overlaps this tile's MFMA + epilogue)
        uint4 nu0, nu1, nu2, nu3, nu4;
        gather_rows<EAB>(hB, eaB, ea, sN, dN, idxNc, quad, nu0, nu1, nu2, nu3, nu4);
        // prefetch indices two tiles ahead
        int tileNN = tileN + stride;
        int idxNNc = (tileNN < nTiles) ? min(tileNN * TILE_E + lbase, E - 1) : idxNc;
        int sNN = src[idxNNc], dNN = dst[idxNNc];

        short8 a0 = *(short8*)&cu0, a1 = *(short8*)&cu1, a2 = *(short8*)&cu2,
               a3 = *(short8*)&cu3, a4 = *(short8*)&cu4;
        f32x4 acc[4] = {{0.f, 0.f, 0.f, 0.f}, {0.f, 0.f, 0.f, 0.f},
                        {0.f, 0.f, 0.f, 0.f}, {0.f, 0.f, 0.f, 0.f}};
        #pragma unroll
        for (int t4 = 0; t4 < 4; ++t4) {
            acc[t4] = __builtin_amdgcn_mfma_f32_16x16x32_bf16(a0, bW[t4][0], acc[t4], 0, 0, 0);
            acc[t4] = __builtin_amdgcn_mfma_f32_16x16x32_bf16(a1, bW[t4][1], acc[t4], 0, 0, 0);
            acc[t4] = __builtin_amdgcn_mfma_f32_16x16x32_bf16(a2, bW[t4][2], acc[t4], 0, 0, 0);
            acc[t4] = __builtin_amdgcn_mfma_f32_16x16x32_bf16(a3, bW[t4][3], acc[t4], 0, 0, 0);
            acc[t4] = __builtin_amdgcn_mfma_f32_16x16x32_bf16(a4, bW[t4][4], acc[t4], 0, 0, 0);
        }

        float sres[4];
        #pragma unroll
        for (int r = 0; r < 4; ++r) {
            float v = 0.f;
            #pragma unroll
            for (int t4 = 0; t4 < 4; ++t4)
                v += fmaxf(acc[t4][r] + bmr[t4], 0.f) * w2r[t4];
            #pragma unroll
            for (int m = 1; m < 16; m <<= 1)
                v += __shfl_xor(v, m, 16);
            sres[r] = v;
        }
        if (l15 == 0) {
            int e0 = tile * TILE_E;
            #pragma unroll
            for (int r = 0; r < 4; ++r) {
                int e = e0 + w * 16 + quad * 4 + r;
                if (e < E) out[e] = sres[r] + bb;
            }
        }

        if (!hasNext) break;
        tile = tileN; tileN = tileNN;
        idxc = idxNc; idxNc = idxNNc;
        s = sN; sN = sNN; d = dN; dN = dNN;
        cu0 = nu0; cu1 = nu1; cu2 = nu2; cu3 = nu3; cu4 = nu4;
    }
}

// ---------------------------------------------------------------------------
extern "C" void kernel_launch(void* const* d_in, const int* in_sizes, int n_in,
                              void* d_out, int out_size, void* d_ws, size_t ws_size,
                              hipStream_t stream) {
    const float* x   = (const float*)d_in[0];
    const int*   ei  = (const int*)d_in[1];
    const float* ea  = (const float*)d_in[2];
    const float* W1l = (const float*)d_in[3];
    const float* b1l = (const float*)d_in[4];
    const float* W1r = (const float*)d_in[5];
    const float* W2l = (const float*)d_in[6];
    const float* b2l = (const float*)d_in[7];
    const float* W2r = (const float*)d_in[8];
    const float* Wm1 = (const float*)d_in[9];
    const float* bm1 = (const float*)d_in[10];
    const float* Wm2 = (const float*)d_in[11];
    const float* bm2 = (const float*)d_in[12];
    float* out = (float*)d_out;

    const int N = in_sizes[0] / C;
    const int E = in_sizes[1] / 2;
    const int* src = ei;
    const int* dst = ei + E;

    char* wsb = (char*)d_ws;
    int npad = (N + 1023) & ~1023;
    float* deg_inv = (float*)wsb;                wsb += (size_t)npad * 4;
    unsigned short* xB   = (unsigned short*)wsb; wsb += (size_t)npad * C * 2;
    unsigned short* h1B  = (unsigned short*)wsb; wsb += (size_t)npad * C * 2;
    unsigned short* h2B  = (unsigned short*)wsb; wsb += (size_t)npad * C * 2;
    unsigned short* aggB = (unsigned short*)wsb; wsb += (size_t)npad * C * 2;
    int* degi    = (int*)wsb;                    wsb += (size_t)npad * 4;
    int* rowptr  = (int*)wsb;                    wsb += (size_t)(npad + 64) * 4;
    int* cursor  = (int*)wsb;                    wsb += (size_t)npad * 4;
    int* eSrc    = (int*)wsb;                    wsb += (size_t)E * 4;
    int* partials = (int*)wsb;                   wsb += 64 * 4;
    int* offsets  = (int*)wsb;                   wsb += 64 * 4;
    unsigned short* eaB = (unsigned short*)wsb;  // E*16 bf16 = 25.6 MB (optional)
    size_t used = (size_t)(wsb - (char*)d_ws);
    int useEaB = (ws_size >= used + (size_t)E * 16 * 2) ? 1 : 0;

    int tpb = 256;
    int nb = (N + 1023) / 1024;

    // CSR build (+ fused ea->bf16)
    hipMemsetAsync(degi, 0, (size_t)N * sizeof(int), stream);
    deg_count_ea<<<(2 * E + tpb - 1) / tpb, tpb, 0, stream>>>(dst, degi, ea, eaB, E, useEaB);
    to_bf16<<<((N * C / 8) + tpb - 1) / tpb, tpb, 0, stream>>>(x, xB, N * C / 8);
    scan_partial<<<nb, tpb, 0, stream>>>(degi, rowptr, partials, N);
    scan_offsets<<<1, 64, 0, stream>>>(partials, offsets, nb);
    scan_add<<<(N + tpb - 1) / tpb, tpb, 0, stream>>>(rowptr, offsets, cursor, degi, deg_inv, N, E);
    fill_csr<<<(E + tpb - 1) / tpb, tpb, 0, stream>>>(src, dst, cursor, eSrc, E);

    // layer 1
    csr_agg_bf16<<<(N + 3) / 4, tpb, 0, stream>>>(xB, rowptr, eSrc, deg_inv, aggB, N);
    dense_mfma<<<(N + 63) / 64, tpb, 0, stream>>>(aggB, xB, W1l, W1r, b1l, h1B, N);

    // layer 2
    csr_agg_bf16<<<(N + 3) / 4, tpb, 0, stream>>>(h1B, rowptr, eSrc, deg_inv, aggB, N);
    dense_mfma<<<(N + 63) / 64, tpb, 0, stream>>>(aggB, h1B, W2l, W2r, b2l, h2B, N);

    // edge MLP (pipelined)
    int nTiles = (E + TILE_E - 1) / TILE_E;
    int grid = nTiles < 2048 ? nTiles : 2048;
    if (useEaB)
        edge_mlp_pipe<true><<<grid, tpb, 0, stream>>>(h2B, src, dst, ea, eaB,
                Wm1, bm1, Wm2, bm2, out, E, nTiles);
    else
        edge_mlp_pipe<false><<<grid, tpb, 0, stream>>>(h2B, src, dst, ea, eaB,
                Wm1, bm1, Wm2, bm2, out, E, nTiles);
}